// Round 22
// baseline (875.206 us; speedup 1.0000x reference)
//
#include <hip/hip_runtime.h>
#include <math.h>

// Problem dims (fixed by reference)
#define BB 32
#define CC 8
#define TT 64
#define FF 256
#define HH 512
#define G3 1536
#define NSEQ 256            // BB*CC
#define MROWS 16384         // NSEQ*TT

#define SGB 4               // seq groups (64 seqs each)
#define NGB 16              // N-split ways (32 h-cols each)

typedef _Float16 f16x8 __attribute__((ext_vector_type(8)));
typedef float f32x4 __attribute__((ext_vector_type(4)));

// ---------------- fallback fp32 input GEMM ----------------
#define TMg 128
#define TNg 128
#define TKg 16

__global__ __launch_bounds__(256) void gemm_bias(
    const float* __restrict__ A, const float* __restrict__ W,
    const float* __restrict__ bias, float* __restrict__ C,
    int M, int N, int K)
{
  __shared__ float As[TKg][TMg + 4];
  __shared__ float Ws[TKg][TNg + 4];
  const int bm = blockIdx.y * TMg;
  const int bn = blockIdx.x * TNg;
  const int tid = threadIdx.x;
  const int tx = tid & 15;
  const int ty = tid >> 4;
  float acc[8][8];
#pragma unroll
  for (int i = 0; i < 8; ++i)
#pragma unroll
    for (int j = 0; j < 8; ++j) acc[i][j] = 0.f;

  for (int k0 = 0; k0 < K; k0 += TKg) {
    __syncthreads();
#pragma unroll
    for (int i = 0; i < 8; ++i) {
      int e = i * 256 + tid;
      int r = e >> 4;
      int c = e & 15;
      As[c][r] = A[(size_t)(bm + r) * K + (k0 + c)];
      Ws[c][r] = W[(size_t)(bn + r) * K + (k0 + c)];
    }
    __syncthreads();
#pragma unroll
    for (int k = 0; k < TKg; ++k) {
      float a[8], w[8];
#pragma unroll
      for (int i = 0; i < 8; ++i) a[i] = As[k][ty * 8 + i];
#pragma unroll
      for (int j = 0; j < 8; ++j) w[j] = Ws[k][tx + 16 * j];
#pragma unroll
      for (int i = 0; i < 8; ++i)
#pragma unroll
        for (int j = 0; j < 8; ++j) acc[i][j] = fmaf(a[i], w[j], acc[i][j]);
    }
  }
#pragma unroll
  for (int i = 0; i < 8; ++i) {
    size_t m = (size_t)(bm + ty * 8 + i);
#pragma unroll
    for (int j = 0; j < 8; ++j) {
      int n = bn + tx + 16 * j;
      C[m * N + n] = acc[i][j] + bias[n];
    }
  }
}

// ---------------- fp32 -> fp16 convert (vectorized x8) ----------------
__global__ __launch_bounds__(256) void conv16(
    const float* __restrict__ x, _Float16* __restrict__ xh, int n8)
{
  int i = blockIdx.x * 256 + threadIdx.x;
  if (i < n8) {
    float4 a = reinterpret_cast<const float4*>(x)[i * 2];
    float4 b = reinterpret_cast<const float4*>(x)[i * 2 + 1];
    f16x8 v;
    v[0] = (_Float16)a.x; v[1] = (_Float16)a.y; v[2] = (_Float16)a.z; v[3] = (_Float16)a.w;
    v[4] = (_Float16)b.x; v[5] = (_Float16)b.y; v[6] = (_Float16)b.z; v[7] = (_Float16)b.w;
    reinterpret_cast<f16x8*>(xh)[i] = v;
  }
}

// ---------------- pack W[G3][K] fp32 -> fp16 B-fragments (for input GEMMs) ------------
// P[tile(96)][kc(K/32)][lane(64)][8]; B-frag: n=lane&15 (W row in tile), k=kc*32+(lane>>4)*8+i
__global__ __launch_bounds__(256) void pack_wih(
    const float* __restrict__ W, _Float16* __restrict__ P, int K)
{
  int id = blockIdx.x * 256 + threadIdx.x;
  int lane = id & 63;
  int kcs = K >> 5;
  int t6 = id >> 6;
  int kc = t6 % kcs;
  int tile = t6 / kcs;
  if (tile >= 96) return;
  int row = tile * 16 + (lane & 15);
  int k0 = kc * 32 + ((lane >> 4) * 8);
  const float* src = W + (size_t)row * K + k0;
  f16x8 v;
#pragma unroll
  for (int i = 0; i < 8; ++i) v[i] = (_Float16)src[i];
  *reinterpret_cast<f16x8*>(P + (size_t)id * 8) = v;
}

// ---------------- pack Whh[G3][HH] -> fp16 B-fragments, 16-way N-split order ----------
// P[ng(16)][tl(6)][kc(16)][lane(64)][8]; tl = gate*2 + sub; gt = gate*32 + ng*2 + sub
// (r12-validated layout: absmax = 0.0)
__global__ __launch_bounds__(256) void pack_whh(
    const float* __restrict__ W, _Float16* __restrict__ P)
{
  int id = blockIdx.x * 256 + threadIdx.x;    // 0 .. 98303
  int lane = id & 63;
  int kc = (id >> 6) & 15;
  int tidx = id >> 10;                        // 0..95 = ng*6 + tl
  int ng = tidx / 6;
  int tl = tidx % 6;
  int g = tl >> 1, sub = tl & 1;
  int gt = g * 32 + ng * 2 + sub;             // global 16-row tile of Whh
  int row = gt * 16 + (lane & 15);
  int k0 = kc * 32 + ((lane >> 4) * 8);
  const float* src = W + (size_t)row * HH + k0;
  f16x8 v;
#pragma unroll
  for (int i = 0; i < 8; ++i) v[i] = (_Float16)src[i];
  *reinterpret_cast<f16x8*>(P + (size_t)id * 8) = v;
}

// ---------------- MFMA input GEMM (r14-proven): C = A(fp16) @ Wpack^T + bias ----------
__device__ __forceinline__ void gload16g(const _Float16* g, _Float16* l) {
  __builtin_amdgcn_global_load_lds(
      (const __attribute__((address_space(1))) unsigned int*)g,
      (__attribute__((address_space(3))) unsigned int*)l, 16, 0, 0);
}

__global__ __launch_bounds__(256, 2) void gemm_mfma(
    const _Float16* __restrict__ A,   // [MROWS][K] fp16
    const _Float16* __restrict__ Bp,  // packed [96][K/32][64][8]
    const float* __restrict__ bias,   // [G3]
    float* __restrict__ C,            // [MROWS][G3]
    int K)
{
  __shared__ __align__(16) _Float16 As[2][128][36];   // 18.4 KB padded
  __shared__ __align__(16) _Float16 Bs[2][8 * 512];   // 16 KB (frag order)

  const int tid = threadIdx.x;
  const int lane = tid & 63;
  const int wv = tid >> 6;
  const int wm = wv >> 1, wn = wv & 1;
  const int bnT = blockIdx.x * 8;             // first of 8 n-tiles
  const int bm = blockIdx.y * 128;
  const int kcs = K >> 5;

  const int arow = lane & 15;
  const int agrp = lane >> 4;
  const int dcol = lane & 15;
  const int mrow = (lane >> 4) * 4;

  f32x4 acc[4][4];
#pragma unroll
  for (int i = 0; i < 4; ++i)
#pragma unroll
    for (int j = 0; j < 4; ++j) acc[i][j] = (f32x4){0.f, 0.f, 0.f, 0.f};

  auto stageA = [&](int s, int b) {
#pragma unroll
    for (int p = 0; p < 2; ++p) {
      int idx = p * 256 + tid;
      int row = idx >> 2;
      int cs = idx & 3;
      f16x8 v = *reinterpret_cast<const f16x8*>(
          A + (size_t)(bm + row) * K + s * 32 + cs * 8);
      *reinterpret_cast<f16x8*>(&As[b][row][cs * 8]) = v;
    }
  };
  auto stageB = [&](int s, int b) {
#pragma unroll
    for (int q = 0; q < 2; ++q) {
      int nt = wv * 2 + q;
      const _Float16* src = Bp + ((size_t)((bnT + nt) * kcs + s) * 64 + lane) * 8;
      gload16g(src, &Bs[b][nt * 512]);
    }
  };

  stageA(0, 0);
  stageB(0, 0);
  __syncthreads();

  for (int s = 0; s < kcs; ++s) {
    const int b = s & 1;
    if (s + 1 < kcs) {
      stageA(s + 1, b ^ 1);
      stageB(s + 1, b ^ 1);
    }
    f16x8 af[4], bf[4];
#pragma unroll
    for (int mt = 0; mt < 4; ++mt)
      af[mt] = *reinterpret_cast<const f16x8*>(&As[b][wm * 64 + mt * 16 + arow][agrp * 8]);
#pragma unroll
    for (int nt = 0; nt < 4; ++nt)
      bf[nt] = *reinterpret_cast<const f16x8*>(&Bs[b][(wn * 4 + nt) * 512 + lane * 8]);
#pragma unroll
    for (int mt = 0; mt < 4; ++mt)
#pragma unroll
      for (int nt = 0; nt < 4; ++nt)
        acc[mt][nt] = __builtin_amdgcn_mfma_f32_16x16x32_f16(af[mt], bf[nt], acc[mt][nt], 0, 0, 0);
    __syncthreads();
  }

  // ---- epilogue: bias + store ----
#pragma unroll
  for (int nt = 0; nt < 4; ++nt) {
    const int n = (bnT + wn * 4 + nt) * 16 + dcol;
    const float bv = bias[n];
#pragma unroll
    for (int mt = 0; mt < 4; ++mt) {
      const size_t m0 = (size_t)(bm + wm * 64 + mt * 16 + mrow);
#pragma unroll
      for (int r = 0; r < 4; ++r)
        C[(m0 + r) * G3 + n] = acc[mt][nt][r] + bv;
    }
  }
}

// ---------------- MFMA recurrent scan: LDS-persistent weights + fenceless exchange ----
// r12's weight/compute structure (validated absmax=0.0) + r18's fenceless protocol
// (validated absmax=6e-5): 64 blocks = 4 seq-groups (64 seqs) x 16 N-groups (32 cols),
// 512 threads (8 waves). 96 KB weight slice staged into LDS ONCE via global_load_lds
// -> ZERO per-step weight traffic (the ~2.5 us/step warm-L2 re-read is gone; LDS is
// untouched by any cache op, and there are no more acquire-invalidates anyway).
// A-frags read DIRECTLY from hx via sc0/sc1 bypass loads (+vmcnt+sched_barrier, rule
// #18); h stores sc0/sc1; publish = vmcnt(0) -> barrier -> relaxed flag; consumers:
// 16 relaxed poller lanes. WAR parity argument identical to r14-r20.
#define GLH(k, offs)                                                              \
  asm volatile("global_load_dwordx4 %0, %1, off offset:" offs " sc0 sc1"          \
               : "=&v"(af[k]) : "v"(hbase));

__global__ __launch_bounds__(512, 1) void gru_scan_mfma(
    const float* __restrict__ gi,      // [NSEQ][TT][G3]
    const _Float16* __restrict__ packW,
    const float* __restrict__ bhh,     // [G3]
    float* __restrict__ hfin,          // [NSEQ][HH]
    _Float16* __restrict__ yout,       // [NSEQ][TT][HH] fp16 or nullptr
    _Float16* __restrict__ hx,         // [2][NSEQ][HH] exchange (LLC-only via sc0/sc1)
    unsigned int* __restrict__ flags)  // [SGB][NGB][TT], zeroed pre-launch
{
  __shared__ __align__(16) _Float16 wlds[6 * 16 * 64 * 8];   // 96 KB, persistent

  const int tid = threadIdx.x;
  const int lane = tid & 63;
  const int w = tid >> 6;                     // wave 0..7
  const int bid = blockIdx.x;
  const int sg = bid & 3;                     // seq group
  const int ng = bid >> 2;                    // N group 0..15
  const int seq0 = sg * 64;

  const int m = w >> 1;                       // m-tile 0..3 (16 seqs each)
  const int p = w & 1;                        // col subtile 0..1
  const int arow16 = lane & 15;               // A-frag row within m-tile
  const int agrp = lane >> 4;                 // A-frag k-group
  const int dcol = lane & 15;                 // D-frag col within tile
  const int mrow = (lane >> 4) * 4;           // D-frag first row within m-tile

  const int cg = ng * 32 + p * 16 + dcol;     // this lane's h column (global)
  const int seqm = seq0 + m * 16;             // this wave's seq base

  // ---- one-time: stage this block's 96 KB weight slice into LDS (r12-proven) ----
  {
    const _Float16* slice = packW + (size_t)ng * (6 * 16 * 64 * 8);
#pragma unroll 4
    for (int it = 0; it < 12; ++it) {
      int blk = it * 8 + w;                               // 0..95 chunks of 1 KB
      gload16g(slice + (size_t)(blk * 64 + lane) * 8,     // per-lane global src
               &wlds[(size_t)(blk * 64) * 8]);            // wave-uniform LDS base
    }
  }

  const float bhr = bhh[cg];
  const float bhz = bhh[HH + cg];
  const float bhn = bhh[2 * HH + cg];

  const int tR = p, tZ = 2 + p, tN = 4 + p;   // this wave's 3 gate tiles in wlds

  float hold[4] = {0.f, 0.f, 0.f, 0.f};

  __syncthreads();   // weight staging complete (barrier drains vmcnt)

  for (int t = 0; t < TT; ++t) {
    const int cb = t & 1;
    const int nb = cb ^ 1;

    // ---- gi loads (prev-kernel data; issue before the poll) ----
    float gir[4], giz[4], gin[4];
#pragma unroll
    for (int r = 0; r < 4; ++r) {
      const float* p0 = gi + ((size_t)(seqm + mrow + r) * TT + t) * G3;
      gir[r] = p0[cg];
      giz[r] = p0[HH + cg];
      gin[r] = p0[2 * HH + cg];
    }

    f32x4 aR = {0.f,0.f,0.f,0.f}, aZ = {0.f,0.f,0.f,0.f}, aN = {0.f,0.f,0.f,0.f};

    if (t > 0) {
      // 16 relaxed poller lanes, one per producer of this seq-group
      if (tid < NGB) {
        const unsigned int* fp = &flags[((size_t)sg * NGB + tid) * TT + (t - 1)];
        while (__hip_atomic_load(fp, __ATOMIC_RELAXED, __HIP_MEMORY_SCOPE_AGENT) == 0u) {}
      }
      __syncthreads();

      // A-frags DIRECT from hx[cb] via sc0/sc1 bypass (LLC-direct, cache-proof)
      f16x8 af[16];
      const _Float16* hbase = hx + (size_t)cb * NSEQ * HH
                              + (size_t)(seqm + arow16) * HH + agrp * 8;
      GLH(0, "0")    GLH(1, "64")   GLH(2, "128")  GLH(3, "192")
      GLH(4, "256")  GLH(5, "320")  GLH(6, "384")  GLH(7, "448")
      GLH(8, "512")  GLH(9, "576")  GLH(10, "640") GLH(11, "704")
      GLH(12, "768") GLH(13, "832") GLH(14, "896") GLH(15, "960")
      asm volatile("s_waitcnt vmcnt(0)" ::: "memory");
      __builtin_amdgcn_sched_barrier(0);

      // 3 gate tiles from LDS-persistent weights (conflict-free ds_read_b128)
#pragma unroll
      for (int kc = 0; kc < 16; ++kc) {
        f16x8 br = *reinterpret_cast<const f16x8*>(&wlds[(size_t)((tR * 16 + kc) * 64 + lane) * 8]);
        f16x8 bz = *reinterpret_cast<const f16x8*>(&wlds[(size_t)((tZ * 16 + kc) * 64 + lane) * 8]);
        f16x8 bn = *reinterpret_cast<const f16x8*>(&wlds[(size_t)((tN * 16 + kc) * 64 + lane) * 8]);
        aR = __builtin_amdgcn_mfma_f32_16x16x32_f16(af[kc], br, aR, 0, 0, 0);
        aZ = __builtin_amdgcn_mfma_f32_16x16x32_f16(af[kc], bz, aZ, 0, 0, 0);
        aN = __builtin_amdgcn_mfma_f32_16x16x32_f16(af[kc], bn, aN, 0, 0, 0);
      }
    }
    // t==0: h=0 -> preacts are just biases (acc stays 0)

    // ---- register-local gate epilogue: 4 seqs x 1 col per lane ----
#pragma unroll
    for (int r = 0; r < 4; ++r) {
      float hr = aR[r] + bhr;
      float hz = aZ[r] + bhz;
      float hn = aN[r] + bhn;
      float rr = __builtin_amdgcn_rcpf(1.f + __expf(-(gir[r] + hr)));
      float zz = __builtin_amdgcn_rcpf(1.f + __expf(-(giz[r] + hz)));
      float ex = __expf(2.f * (gin[r] + rr * hn));
      float nn = 1.f - 2.f * __builtin_amdgcn_rcpf(ex + 1.f);
      float hnew = nn + zz * (hold[r] - nn);
      hold[r] = hnew;
      // hx store: sc0/sc1 write-through to LLC (no dirty L2)
      {
        _Float16 h16 = (_Float16)hnew;
        unsigned int hv32 = (unsigned int)__builtin_bit_cast(unsigned short, h16);
        _Float16* addr = hx + (size_t)nb * NSEQ * HH
                         + (size_t)(seqm + mrow + r) * HH + cg;
        asm volatile("global_store_short %0, %1, off sc0 sc1"
                     :: "v"(addr), "v"(hv32) : "memory");
      }
      if (yout)
        yout[((size_t)(seqm + mrow + r) * TT + t) * HH + cg] = (_Float16)hnew;
    }

    // publish: drain stores to LLC, barrier, relaxed flag store
    asm volatile("s_waitcnt vmcnt(0)" ::: "memory");
    __syncthreads();
    if (tid == 0)
      __hip_atomic_store(&flags[((size_t)sg * NGB + ng) * TT + t], 1u,
                         __ATOMIC_RELAXED, __HIP_MEMORY_SCOPE_AGENT);
  }

#pragma unroll
  for (int r = 0; r < 4; ++r)
    hfin[(size_t)(seqm + mrow + r) * HH + cg] = hold[r];
}

// ---------------- fallback fp32 scan (row-streaming) ----------------
#define QS 4
#define SCTH 512
__global__ __launch_bounds__(SCTH) void gru_scan2f(
    const float* __restrict__ gi, const float* __restrict__ W,
    const float* __restrict__ bhh, float* __restrict__ hfin,
    float* __restrict__ yout)
{
  __shared__ __align__(16) float hsl[HH][QS];
  const int col = threadIdx.x;
  const int seq0 = blockIdx.x * QS;
  const float bh0 = bhh[col];
  const float bh1 = bhh[HH + col];
  const float bh2 = bhh[2 * HH + col];
  const float* w0p = W + (size_t)col * HH;
  const float* w1p = W + (size_t)(HH + col) * HH;
  const float* w2p = W + (size_t)(2 * HH + col) * HH;

  *reinterpret_cast<float4*>(&hsl[col][0]) = make_float4(0.f, 0.f, 0.f, 0.f);
  __syncthreads();

  for (int t = 0; t < TT; ++t) {
    float acc0[QS], acc1[QS], acc2[QS];
#pragma unroll
    for (int s = 0; s < QS; ++s) { acc0[s] = bh0; acc1[s] = bh1; acc2[s] = bh2; }
    float4 ho = *reinterpret_cast<const float4*>(&hsl[col][0]);
    float hold[QS] = {ho.x, ho.y, ho.z, ho.w};
#pragma unroll 2
    for (int k0 = 0; k0 < HH; k0 += 4) {
      float w[3][4];
      float4 a = *reinterpret_cast<const float4*>(&w0p[k0]);
      w[0][0] = a.x; w[0][1] = a.y; w[0][2] = a.z; w[0][3] = a.w;
      float4 b = *reinterpret_cast<const float4*>(&w1p[k0]);
      w[1][0] = b.x; w[1][1] = b.y; w[1][2] = b.z; w[1][3] = b.w;
      float4 c = *reinterpret_cast<const float4*>(&w2p[k0]);
      w[2][0] = c.x; w[2][1] = c.y; w[2][2] = c.z; w[2][3] = c.w;
#pragma unroll
      for (int kk = 0; kk < 4; ++kk) {
        float4 h4 = *reinterpret_cast<const float4*>(&hsl[k0 + kk][0]);
        float hq[4] = {h4.x, h4.y, h4.z, h4.w};
#pragma unroll
        for (int s = 0; s < QS; ++s) {
          acc0[s] = fmaf(hq[s], w[0][kk], acc0[s]);
          acc1[s] = fmaf(hq[s], w[1][kk], acc1[s]);
          acc2[s] = fmaf(hq[s], w[2][kk], acc2[s]);
        }
      }
    }
    __syncthreads();
    float hnew[QS];
#pragma unroll
    for (int s = 0; s < QS; ++s) {
      size_t grow = ((size_t)(seq0 + s) * TT + t) * G3;
      float ir = gi[grow + col];
      float iz = gi[grow + HH + col];
      float inn = gi[grow + 2 * HH + col];
      float r = 1.f / (1.f + expf(-(ir + acc0[s])));
      float z = 1.f / (1.f + expf(-(iz + acc1[s])));
      float nn = tanhf(inn + r * acc2[s]);
      hnew[s] = (1.f - z) * nn + z * hold[s];
      if (yout) yout[((size_t)(seq0 + s) * TT + t) * HH + col] = hnew[s];
    }
    *reinterpret_cast<float4*>(&hsl[col][0]) =
        make_float4(hnew[0], hnew[1], hnew[2], hnew[3]);
    __syncthreads();
  }
#pragma unroll
  for (int s = 0; s < QS; ++s)
    hfin[(size_t)(seq0 + s) * HH + col] = hsl[col][s];
}

// ---------------- final FC + channel mean ----------------
__global__ __launch_bounds__(256) void fc_mean(
    const float* __restrict__ hfin, const float* __restrict__ fcW,
    const float* __restrict__ fcb, float* __restrict__ out)
{
  __shared__ float red[256];
  const int b = blockIdx.x;
  const int tid = threadIdx.x;
  float sum = 0.f;
  for (int e = tid; e < CC * HH; e += 256) {
    int c = e >> 9;
    int k = e & (HH - 1);
    sum += hfin[(size_t)(b * CC + c) * HH + k] * fcW[k];
  }
  red[tid] = sum;
  __syncthreads();
  for (int w = 128; w > 0; w >>= 1) {
    if (tid < w) red[tid] += red[tid + w];
    __syncthreads();
  }
  if (tid == 0) out[b] = red[0] * (1.f / CC) + fcb[0];
}

extern "C" void kernel_launch(void* const* d_in, const int* in_sizes, int n_in,
                              void* d_out, int out_size, void* d_ws, size_t ws_size,
                              hipStream_t stream)
{
  const float* x    = (const float*)d_in[0];
  const float* Wih0 = (const float*)d_in[1];
  const float* Whh0 = (const float*)d_in[2];
  const float* bih0 = (const float*)d_in[3];
  const float* bhh0 = (const float*)d_in[4];
  const float* Wih1 = (const float*)d_in[5];
  const float* Whh1 = (const float*)d_in[6];
  const float* bih1 = (const float*)d_in[7];
  const float* bhh1 = (const float*)d_in[8];
  const float* fcW  = (const float*)d_in[9];
  const float* fcb  = (const float*)d_in[10];
  float* out = (float*)d_out;

  // ws layout (fast path):
  //   gi    [MROWS][G3] fp32  100,663,296 @ 0
  //   y0h   [MROWS][HH] fp16   16,777,216 @ 100,663,296
  //   xh    [MROWS][FF] fp16    8,388,608 @ 117,440,512
  //   pWih  fp16 (K<=512)       1,572,864 @ 125,829,120
  //   pWhh  fp16                1,572,864 @ 127,401,984
  //   hx    [2][NSEQ][HH] fp16    524,288 @ 128,974,848
  //   flags [SGB][NGB][TT] u32     16,384 @ 129,499,136
  //   hfin  [NSEQ][HH] fp32       524,288 @ 134,217,728  (shared w/ fallback layout)
  char* ws = (char*)d_ws;
  float* gibuf = (float*)ws;
  _Float16* y0h  = (_Float16*)(ws + 100663296ull);
  _Float16* xh   = (_Float16*)(ws + 117440512ull);
  _Float16* pWih = (_Float16*)(ws + 125829120ull);
  _Float16* pWhh = (_Float16*)(ws + 127401984ull);
  _Float16* hx   = (_Float16*)(ws + 128974848ull);
  unsigned int* flags = (unsigned int*)(ws + 129499136ull);
  float* hfin = (float*)(ws + 134217728ull);
  float* y0f  = (float*)(ws + 100663296ull);   // fallback fp32 y0 (33.5 MB)
  const bool mfma_ok = (ws_size >= 134742016ull);

  if (mfma_ok) {
    // layer 0: x->fp16, pack Wih0, MFMA GEMM (K=256)
    conv16<<<dim3((MROWS * FF / 8 + 255) / 256), 256, 0, stream>>>(x, xh, MROWS * FF / 8);
    pack_wih<<<dim3(192), 256, 0, stream>>>(Wih0, pWih, FF);
    gemm_mfma<<<dim3(12, 128), 256, 0, stream>>>(xh, pWih, bih0, gibuf, FF);

    // layer 0 scan
    pack_whh<<<dim3(384), 256, 0, stream>>>(Whh0, pWhh);
    hipMemsetAsync(flags, 0, SGB * NGB * TT * sizeof(unsigned int), stream);
    gru_scan_mfma<<<dim3(SGB * NGB), 512, 0, stream>>>(gibuf, pWhh, bhh0, hfin, y0h, hx, flags);

    // layer 1: pack Wih1, MFMA GEMM (K=512) on fp16 y0
    pack_wih<<<dim3(384), 256, 0, stream>>>(Wih1, pWih, HH);
    gemm_mfma<<<dim3(12, 128), 256, 0, stream>>>(y0h, pWih, bih1, gibuf, HH);

    // layer 1 scan
    pack_whh<<<dim3(384), 256, 0, stream>>>(Whh1, pWhh);
    hipMemsetAsync(flags, 0, SGB * NGB * TT * sizeof(unsigned int), stream);
    gru_scan_mfma<<<dim3(SGB * NGB), 512, 0, stream>>>(gibuf, pWhh, bhh1, hfin, nullptr, hx, flags);
  } else {
    gemm_bias<<<dim3(G3 / TNg, MROWS / TMg), 256, 0, stream>>>(x, Wih0, bih0, gibuf, MROWS, G3, FF);
    gru_scan2f<<<dim3(NSEQ / QS), SCTH, 0, stream>>>(gibuf, Whh0, bhh0, hfin, y0f);
    gemm_bias<<<dim3(G3 / TNg, MROWS / TMg), 256, 0, stream>>>(y0f, Wih1, bih1, gibuf, MROWS, G3, HH);
    gru_scan2f<<<dim3(NSEQ / QS), SCTH, 0, stream>>>(gibuf, Whh1, bhh1, hfin, nullptr);
  }

  fc_mean<<<dim3(BB), 256, 0, stream>>>(hfin, fcW, fcb, out);
}

// Round 23
// 628.804 us; speedup vs baseline: 1.3919x; 1.3919x over previous
//
#include <hip/hip_runtime.h>
#include <math.h>

// Problem dims (fixed by reference)
#define BB 32
#define CC 8
#define TT 64
#define FF 256
#define HH 512
#define G3 1536
#define NSEQ 256            // BB*CC
#define MROWS 16384         // NSEQ*TT

#define SGRP 16             // sequence groups (16 seqs each)
#define NGRP 4              // N-split ways (384 preact cols each)

typedef _Float16 f16x8 __attribute__((ext_vector_type(8)));
typedef float f32x4 __attribute__((ext_vector_type(4)));

// ---------------- fallback fp32 input GEMM ----------------
#define TMg 128
#define TNg 128
#define TKg 16

__global__ __launch_bounds__(256) void gemm_bias(
    const float* __restrict__ A, const float* __restrict__ W,
    const float* __restrict__ bias, float* __restrict__ C,
    int M, int N, int K)
{
  __shared__ float As[TKg][TMg + 4];
  __shared__ float Ws[TKg][TNg + 4];
  const int bm = blockIdx.y * TMg;
  const int bn = blockIdx.x * TNg;
  const int tid = threadIdx.x;
  const int tx = tid & 15;
  const int ty = tid >> 4;
  float acc[8][8];
#pragma unroll
  for (int i = 0; i < 8; ++i)
#pragma unroll
    for (int j = 0; j < 8; ++j) acc[i][j] = 0.f;

  for (int k0 = 0; k0 < K; k0 += TKg) {
    __syncthreads();
#pragma unroll
    for (int i = 0; i < 8; ++i) {
      int e = i * 256 + tid;
      int r = e >> 4;
      int c = e & 15;
      As[c][r] = A[(size_t)(bm + r) * K + (k0 + c)];
      Ws[c][r] = W[(size_t)(bn + r) * K + (k0 + c)];
    }
    __syncthreads();
#pragma unroll
    for (int k = 0; k < TKg; ++k) {
      float a[8], w[8];
#pragma unroll
      for (int i = 0; i < 8; ++i) a[i] = As[k][ty * 8 + i];
#pragma unroll
      for (int j = 0; j < 8; ++j) w[j] = Ws[k][tx + 16 * j];
#pragma unroll
      for (int i = 0; i < 8; ++i)
#pragma unroll
        for (int j = 0; j < 8; ++j) acc[i][j] = fmaf(a[i], w[j], acc[i][j]);
    }
  }
#pragma unroll
  for (int i = 0; i < 8; ++i) {
    size_t m = (size_t)(bm + ty * 8 + i);
#pragma unroll
    for (int j = 0; j < 8; ++j) {
      int n = bn + tx + 16 * j;
      C[m * N + n] = acc[i][j] + bias[n];
    }
  }
}

// ---------------- fp32 -> fp16 convert (vectorized x8) ----------------
__global__ __launch_bounds__(256) void conv16(
    const float* __restrict__ x, _Float16* __restrict__ xh, int n8)
{
  int i = blockIdx.x * 256 + threadIdx.x;
  if (i < n8) {
    float4 a = reinterpret_cast<const float4*>(x)[i * 2];
    float4 b = reinterpret_cast<const float4*>(x)[i * 2 + 1];
    f16x8 v;
    v[0] = (_Float16)a.x; v[1] = (_Float16)a.y; v[2] = (_Float16)a.z; v[3] = (_Float16)a.w;
    v[4] = (_Float16)b.x; v[5] = (_Float16)b.y; v[6] = (_Float16)b.z; v[7] = (_Float16)b.w;
    reinterpret_cast<f16x8*>(xh)[i] = v;
  }
}

// ---------------- pack W[G3][K] fp32 -> fp16 B-fragments ----------------
// P[tile(96)][kc(K/32)][lane(64)][8]; B-frag: n=lane&15 (W row in tile), k=kc*32+(lane>>4)*8+i
__global__ __launch_bounds__(256) void pack_wih(
    const float* __restrict__ W, _Float16* __restrict__ P, int K)
{
  int id = blockIdx.x * 256 + threadIdx.x;
  int lane = id & 63;
  int kcs = K >> 5;
  int t6 = id >> 6;
  int kc = t6 % kcs;
  int tile = t6 / kcs;
  if (tile >= 96) return;
  int row = tile * 16 + (lane & 15);
  int k0 = kc * 32 + ((lane >> 4) * 8);
  const float* src = W + (size_t)row * K + k0;
  f16x8 v;
#pragma unroll
  for (int i = 0; i < 8; ++i) v[i] = (_Float16)src[i];
  *reinterpret_cast<f16x8*>(P + (size_t)id * 8) = v;
}

// ---------------- pack Whh[G3][HH] -> fp16 B-fragments, 4-way N-split order ------
// P[ng(4)][tl(24)][kc(16)][lane(64)][8]; tl = gate*8 + sub; global tile = gate*32+ng*8+sub
__global__ __launch_bounds__(256) void pack_whh(
    const float* __restrict__ W, _Float16* __restrict__ P)
{
  int id = blockIdx.x * 256 + threadIdx.x;    // 0 .. 98303
  int lane = id & 63;
  int kc = (id >> 6) & 15;
  int tidx = id >> 10;                        // 0..95 = ng*24 + tl
  int ng = tidx / 24;
  int tl = tidx % 24;
  int g = tl >> 3, sub = tl & 7;
  int gt = g * 32 + ng * 8 + sub;
  int row = gt * 16 + (lane & 15);
  int k0 = kc * 32 + ((lane >> 4) * 8);
  const float* src = W + (size_t)row * HH + k0;
  f16x8 v;
#pragma unroll
  for (int i = 0; i < 8; ++i) v[i] = (_Float16)src[i];
  *reinterpret_cast<f16x8*>(P + (size_t)id * 8) = v;
}

// ---------------- MFMA input GEMM (r14-proven): C = A(fp16) @ Wpack^T + bias ----------
__device__ __forceinline__ void gload16g(const _Float16* g, _Float16* l) {
  __builtin_amdgcn_global_load_lds(
      (const __attribute__((address_space(1))) unsigned int*)g,
      (__attribute__((address_space(3))) unsigned int*)l, 16, 0, 0);
}

__global__ __launch_bounds__(256, 2) void gemm_mfma(
    const _Float16* __restrict__ A,   // [MROWS][K] fp16
    const _Float16* __restrict__ Bp,  // packed [96][K/32][64][8]
    const float* __restrict__ bias,   // [G3]
    float* __restrict__ C,            // [MROWS][G3]
    int K)
{
  __shared__ __align__(16) _Float16 As[2][128][36];   // 18.4 KB padded
  __shared__ __align__(16) _Float16 Bs[2][8 * 512];   // 16 KB (frag order)

  const int tid = threadIdx.x;
  const int lane = tid & 63;
  const int wv = tid >> 6;
  const int wm = wv >> 1, wn = wv & 1;
  const int bnT = blockIdx.x * 8;             // first of 8 n-tiles
  const int bm = blockIdx.y * 128;
  const int kcs = K >> 5;

  const int arow = lane & 15;
  const int agrp = lane >> 4;
  const int dcol = lane & 15;
  const int mrow = (lane >> 4) * 4;

  f32x4 acc[4][4];
#pragma unroll
  for (int i = 0; i < 4; ++i)
#pragma unroll
    for (int j = 0; j < 4; ++j) acc[i][j] = (f32x4){0.f, 0.f, 0.f, 0.f};

  auto stageA = [&](int s, int b) {
#pragma unroll
    for (int p = 0; p < 2; ++p) {
      int idx = p * 256 + tid;
      int row = idx >> 2;
      int cs = idx & 3;
      f16x8 v = *reinterpret_cast<const f16x8*>(
          A + (size_t)(bm + row) * K + s * 32 + cs * 8);
      *reinterpret_cast<f16x8*>(&As[b][row][cs * 8]) = v;
    }
  };
  auto stageB = [&](int s, int b) {
#pragma unroll
    for (int q = 0; q < 2; ++q) {
      int nt = wv * 2 + q;
      const _Float16* src = Bp + ((size_t)((bnT + nt) * kcs + s) * 64 + lane) * 8;
      gload16g(src, &Bs[b][nt * 512]);
    }
  };

  stageA(0, 0);
  stageB(0, 0);
  __syncthreads();

  for (int s = 0; s < kcs; ++s) {
    const int b = s & 1;
    if (s + 1 < kcs) {
      stageA(s + 1, b ^ 1);
      stageB(s + 1, b ^ 1);
    }
    f16x8 af[4], bf[4];
#pragma unroll
    for (int mt = 0; mt < 4; ++mt)
      af[mt] = *reinterpret_cast<const f16x8*>(&As[b][wm * 64 + mt * 16 + arow][agrp * 8]);
#pragma unroll
    for (int nt = 0; nt < 4; ++nt)
      bf[nt] = *reinterpret_cast<const f16x8*>(&Bs[b][(wn * 4 + nt) * 512 + lane * 8]);
#pragma unroll
    for (int mt = 0; mt < 4; ++mt)
#pragma unroll
      for (int nt = 0; nt < 4; ++nt)
        acc[mt][nt] = __builtin_amdgcn_mfma_f32_16x16x32_f16(af[mt], bf[nt], acc[mt][nt], 0, 0, 0);
    __syncthreads();
  }

  // ---- epilogue: bias + store ----
#pragma unroll
  for (int nt = 0; nt < 4; ++nt) {
    const int n = (bnT + wn * 4 + nt) * 16 + dcol;
    const float bv = bias[n];
#pragma unroll
    for (int mt = 0; mt < 4; ++mt) {
      const size_t m0 = (size_t)(bm + wm * 64 + mt * 16 + mrow);
#pragma unroll
      for (int r = 0; r < 4; ++r)
        C[(m0 + r) * G3 + n] = acc[mt][nt][r] + bv;
    }
  }
}

// ---------------- MFMA recurrent scan (r19-proven BEST: fenceless sc0/sc1 exchange,
// hoisted weight loads overlapped with poll, gi pre-poll issue) ----------
#define SPB2 16
#define HSTR 520

#define LOADW(buf, g)                                                            \
  {                                                                              \
    const _Float16* _s = packW +                                                 \
        (((size_t)(ng * 24 + (g) * 8 + wid)) * 16) * 512 + (size_t)lane * 8;     \
    _Pragma("unroll")                                                            \
    for (int kc = 0; kc < 16; ++kc)                                              \
      buf[kc] = *reinterpret_cast<const f16x8*>(_s + (size_t)kc * 512);          \
  }

#define MF16(buf, acc)                                                           \
  {                                                                              \
    _Pragma("unroll")                                                            \
    for (int kc = 0; kc < 16; ++kc) {                                            \
      f16x8 _ha = *reinterpret_cast<const f16x8*>(&hs[arow][kc * 32 + agrp * 8]); \
      acc = __builtin_amdgcn_mfma_f32_16x16x32_f16(_ha, buf[kc], acc, 0, 0, 0);  \
    }                                                                            \
  }

__global__ __launch_bounds__(512, 1) void gru_scan_mfma(
    const float* __restrict__ gi,      // [NSEQ][TT][G3]
    const _Float16* __restrict__ packW,
    const float* __restrict__ bhh,     // [G3]
    float* __restrict__ hfin,          // [NSEQ][HH]
    _Float16* __restrict__ yout,       // [NSEQ][TT][HH] fp16 or nullptr
    _Float16* __restrict__ hx,         // [2][NSEQ][HH] exchange (LLC-only via sc0/sc1)
    unsigned int* __restrict__ flags)  // [SGRP][NGRP][TT], zeroed pre-launch
{
  __shared__ __align__(16) _Float16 hs[SPB2][HSTR];   // 16.6 KB

  const int tid = threadIdx.x;
  const int lane = tid & 63;
  const int wid = tid >> 6;                   // 0..7
  const int bid = blockIdx.x;
  const int sg = bid >> 2;                    // seq group
  const int ng = bid & 3;                     // N group (uniform per XCD: 8 % 4 == 0)
  const int seq0 = sg * SPB2;

  const int arow = lane & 15;
  const int agrp = lane >> 4;
  const int dcol = lane & 15;
  const int mrow = (lane >> 4) * 4;

  const int cg = ng * 128 + wid * 16 + dcol;

  const float bhr = bhh[cg];
  const float bhz = bhh[HH + cg];
  const float bhn = bhh[2 * HH + cg];

  // ---- hoisted weight fragments (re-issued from warm L2 each step, overlapped) ----
  f16x8 wbR[16], wbZ[16], wbN[16];
  LOADW(wbR, 0)
  LOADW(wbZ, 1)
  LOADW(wbN, 2)

  float hold[4] = {0.f, 0.f, 0.f, 0.f};

  for (int e = tid; e < SPB2 * HSTR; e += 512)
    hs[e / HSTR][e % HSTR] = (_Float16)0.f;
  __syncthreads();

  for (int t = 0; t < TT; ++t) {
    // ---- gi loads: prev-kernel data, independent of hx -> issue BEFORE the poll ----
    float gir[4], giz[4], gin[4];
#pragma unroll
    for (int r = 0; r < 4; ++r) {
      const float* p0 = gi + ((size_t)(seq0 + mrow + r) * TT + t) * G3;
      gir[r] = p0[cg];
      giz[r] = p0[HH + cg];
      gin[r] = p0[2 * HH + cg];
    }

    if (t > 0) {
      // 4 relaxed poller lanes, one per producer (separate flag rows; no invalidates)
      if (tid < NGRP) {
        const unsigned int* fp = &flags[((size_t)sg * NGRP + tid) * TT + (t - 1)];
        while (__hip_atomic_load(fp, __ATOMIC_RELAXED, __HIP_MEMORY_SCOPE_AGENT) == 0u) {}
      }
      __syncthreads();
      // copy h(t-1) from hx[t&1] via sc0/sc1 BYPASS loads (LLC-direct, cache-proof)
      {
        const _Float16* src = hx + (size_t)(t & 1) * NSEQ * HH
                              + (size_t)seq0 * HH + (size_t)tid * 16;
        f16x8 v0, v1;
        asm volatile(
            "global_load_dwordx4 %0, %2, off sc0 sc1\n\t"
            "global_load_dwordx4 %1, %2, off offset:16 sc0 sc1\n\t"
            "s_waitcnt vmcnt(0)"
            : "=&v"(v0), "=&v"(v1) : "v"(src) : "memory");
        int e0 = tid * 16;
        int row = e0 >> 9;
        int col = e0 & 511;
        *reinterpret_cast<f16x8*>(&hs[row][col]) = v0;
        *reinterpret_cast<f16x8*>(&hs[row][col + 8]) = v1;
      }
      __syncthreads();
    }

    f32x4 aR = {0.f,0.f,0.f,0.f}, aZ = {0.f,0.f,0.f,0.f}, aN = {0.f,0.f,0.f,0.f};
    MF16(wbR, aR)
    MF16(wbZ, aZ)
    MF16(wbN, aN)

    const int nb = (t + 1) & 1;
#pragma unroll
    for (int r = 0; r < 4; ++r) {
      float hr = aR[r] + bhr;
      float hz = aZ[r] + bhz;
      float hn = aN[r] + bhn;
      float rr = __builtin_amdgcn_rcpf(1.f + __expf(-(gir[r] + hr)));
      float zz = __builtin_amdgcn_rcpf(1.f + __expf(-(giz[r] + hz)));
      float ex = __expf(2.f * (gin[r] + rr * hn));
      float nn = 1.f - 2.f * __builtin_amdgcn_rcpf(ex + 1.f);
      float hnew = nn + zz * (hold[r] - nn);
      hold[r] = hnew;
      // hx store: sc0/sc1 write-through to LLC (no dirty L2)
      {
        _Float16 h16 = (_Float16)hnew;
        unsigned int hv32 = (unsigned int)__builtin_bit_cast(unsigned short, h16);
        _Float16* addr = hx + (size_t)nb * NSEQ * HH
                         + (size_t)(seq0 + mrow + r) * HH + cg;
        asm volatile("global_store_short %0, %1, off sc0 sc1"
                     :: "v"(addr), "v"(hv32) : "memory");
      }
      if (yout)
        yout[((size_t)(seq0 + mrow + r) * TT + t) * HH + cg] = (_Float16)hnew;
    }

    // publish: drain stores to LLC, barrier, relaxed flag store
    asm volatile("s_waitcnt vmcnt(0)" ::: "memory");
    __syncthreads();
    if (tid == 0)
      __hip_atomic_store(&flags[((size_t)sg * NGRP + ng) * TT + t], 1u,
                         __ATOMIC_RELAXED, __HIP_MEMORY_SCOPE_AGENT);
  }

#pragma unroll
  for (int r = 0; r < 4; ++r)
    hfin[(size_t)(seq0 + mrow + r) * HH + cg] = hold[r];
}

// ---------------- fallback fp32 scan (row-streaming) ----------------
#define QS 4
#define SCTH 512
__global__ __launch_bounds__(SCTH) void gru_scan2f(
    const float* __restrict__ gi, const float* __restrict__ W,
    const float* __restrict__ bhh, float* __restrict__ hfin,
    float* __restrict__ yout)
{
  __shared__ __align__(16) float hsl[HH][QS];
  const int col = threadIdx.x;
  const int seq0 = blockIdx.x * QS;
  const float bh0 = bhh[col];
  const float bh1 = bhh[HH + col];
  const float bh2 = bhh[2 * HH + col];
  const float* w0p = W + (size_t)col * HH;
  const float* w1p = W + (size_t)(HH + col) * HH;
  const float* w2p = W + (size_t)(2 * HH + col) * HH;

  *reinterpret_cast<float4*>(&hsl[col][0]) = make_float4(0.f, 0.f, 0.f, 0.f);
  __syncthreads();

  for (int t = 0; t < TT; ++t) {
    float acc0[QS], acc1[QS], acc2[QS];
#pragma unroll
    for (int s = 0; s < QS; ++s) { acc0[s] = bh0; acc1[s] = bh1; acc2[s] = bh2; }
    float4 ho = *reinterpret_cast<const float4*>(&hsl[col][0]);
    float hold[QS] = {ho.x, ho.y, ho.z, ho.w};
#pragma unroll 2
    for (int k0 = 0; k0 < HH; k0 += 4) {
      float w[3][4];
      float4 a = *reinterpret_cast<const float4*>(&w0p[k0]);
      w[0][0] = a.x; w[0][1] = a.y; w[0][2] = a.z; w[0][3] = a.w;
      float4 b = *reinterpret_cast<const float4*>(&w1p[k0]);
      w[1][0] = b.x; w[1][1] = b.y; w[1][2] = b.z; w[1][3] = b.w;
      float4 c = *reinterpret_cast<const float4*>(&w2p[k0]);
      w[2][0] = c.x; w[2][1] = c.y; w[2][2] = c.z; w[2][3] = c.w;
#pragma unroll
      for (int kk = 0; kk < 4; ++kk) {
        float4 h4 = *reinterpret_cast<const float4*>(&hsl[k0 + kk][0]);
        float hq[4] = {h4.x, h4.y, h4.z, h4.w};
#pragma unroll
        for (int s = 0; s < QS; ++s) {
          acc0[s] = fmaf(hq[s], w[0][kk], acc0[s]);
          acc1[s] = fmaf(hq[s], w[1][kk], acc1[s]);
          acc2[s] = fmaf(hq[s], w[2][kk], acc2[s]);
        }
      }
    }
    __syncthreads();
    float hnew[QS];
#pragma unroll
    for (int s = 0; s < QS; ++s) {
      size_t grow = ((size_t)(seq0 + s) * TT + t) * G3;
      float ir = gi[grow + col];
      float iz = gi[grow + HH + col];
      float inn = gi[grow + 2 * HH + col];
      float r = 1.f / (1.f + expf(-(ir + acc0[s])));
      float z = 1.f / (1.f + expf(-(iz + acc1[s])));
      float nn = tanhf(inn + r * acc2[s]);
      hnew[s] = (1.f - z) * nn + z * hold[s];
      if (yout) yout[((size_t)(seq0 + s) * TT + t) * HH + col] = hnew[s];
    }
    *reinterpret_cast<float4*>(&hsl[col][0]) =
        make_float4(hnew[0], hnew[1], hnew[2], hnew[3]);
    __syncthreads();
  }
#pragma unroll
  for (int s = 0; s < QS; ++s)
    hfin[(size_t)(seq0 + s) * HH + col] = hsl[col][s];
}

// ---------------- final FC + channel mean ----------------
__global__ __launch_bounds__(256) void fc_mean(
    const float* __restrict__ hfin, const float* __restrict__ fcW,
    const float* __restrict__ fcb, float* __restrict__ out)
{
  __shared__ float red[256];
  const int b = blockIdx.x;
  const int tid = threadIdx.x;
  float sum = 0.f;
  for (int e = tid; e < CC * HH; e += 256) {
    int c = e >> 9;
    int k = e & (HH - 1);
    sum += hfin[(size_t)(b * CC + c) * HH + k] * fcW[k];
  }
  red[tid] = sum;
  __syncthreads();
  for (int w = 128; w > 0; w >>= 1) {
    if (tid < w) red[tid] += red[tid + w];
    __syncthreads();
  }
  if (tid == 0) out[b] = red[0] * (1.f / CC) + fcb[0];
}

extern "C" void kernel_launch(void* const* d_in, const int* in_sizes, int n_in,
                              void* d_out, int out_size, void* d_ws, size_t ws_size,
                              hipStream_t stream)
{
  const float* x    = (const float*)d_in[0];
  const float* Wih0 = (const float*)d_in[1];
  const float* Whh0 = (const float*)d_in[2];
  const float* bih0 = (const float*)d_in[3];
  const float* bhh0 = (const float*)d_in[4];
  const float* Wih1 = (const float*)d_in[5];
  const float* Whh1 = (const float*)d_in[6];
  const float* bih1 = (const float*)d_in[7];
  const float* bhh1 = (const float*)d_in[8];
  const float* fcW  = (const float*)d_in[9];
  const float* fcb  = (const float*)d_in[10];
  float* out = (float*)d_out;

  // ws layout (fast path):
  //   gi    [MROWS][G3] fp32  100,663,296 @ 0
  //   y0h   [MROWS][HH] fp16   16,777,216 @ 100,663,296
  //   xh    [MROWS][FF] fp16    8,388,608 @ 117,440,512
  //   pWih  fp16 (K<=512)       1,572,864 @ 125,829,120
  //   pWhh  fp16                1,572,864 @ 127,401,984
  //   hx    [2][NSEQ][HH] fp16    524,288 @ 128,974,848
  //   flags [SGRP][NGRP][TT]       16,384 @ 129,499,136
  //   hfin  [NSEQ][HH] fp32       524,288 @ 134,217,728  (shared w/ fallback layout)
  char* ws = (char*)d_ws;
  float* gibuf = (float*)ws;
  _Float16* y0h  = (_Float16*)(ws + 100663296ull);
  _Float16* xh   = (_Float16*)(ws + 117440512ull);
  _Float16* pWih = (_Float16*)(ws + 125829120ull);
  _Float16* pWhh = (_Float16*)(ws + 127401984ull);
  _Float16* hx   = (_Float16*)(ws + 128974848ull);
  unsigned int* flags = (unsigned int*)(ws + 129499136ull);
  float* hfin = (float*)(ws + 134217728ull);
  float* y0f  = (float*)(ws + 100663296ull);   // fallback fp32 y0 (33.5 MB)
  const bool mfma_ok = (ws_size >= 134742016ull);

  if (mfma_ok) {
    // layer 0: x->fp16, pack Wih0, MFMA GEMM (K=256)
    conv16<<<dim3((MROWS * FF / 8 + 255) / 256), 256, 0, stream>>>(x, xh, MROWS * FF / 8);
    pack_wih<<<dim3(192), 256, 0, stream>>>(Wih0, pWih, FF);
    gemm_mfma<<<dim3(12, 128), 256, 0, stream>>>(xh, pWih, bih0, gibuf, FF);

    // layer 0 scan
    pack_whh<<<dim3(384), 256, 0, stream>>>(Whh0, pWhh);
    hipMemsetAsync(flags, 0, SGRP * NGRP * TT * sizeof(unsigned int), stream);
    gru_scan_mfma<<<dim3(SGRP * NGRP), 512, 0, stream>>>(gibuf, pWhh, bhh0, hfin, y0h, hx, flags);

    // layer 1: pack Wih1, MFMA GEMM (K=512) on fp16 y0
    pack_wih<<<dim3(384), 256, 0, stream>>>(Wih1, pWih, HH);
    gemm_mfma<<<dim3(12, 128), 256, 0, stream>>>(y0h, pWih, bih1, gibuf, HH);

    // layer 1 scan
    pack_whh<<<dim3(384), 256, 0, stream>>>(Whh1, pWhh);
    hipMemsetAsync(flags, 0, SGRP * NGRP * TT * sizeof(unsigned int), stream);
    gru_scan_mfma<<<dim3(SGRP * NGRP), 512, 0, stream>>>(gibuf, pWhh, bhh1, hfin, nullptr, hx, flags);
  } else {
    gemm_bias<<<dim3(G3 / TNg, MROWS / TMg), 256, 0, stream>>>(x, Wih0, bih0, gibuf, MROWS, G3, FF);
    gru_scan2f<<<dim3(NSEQ / QS), SCTH, 0, stream>>>(gibuf, Whh0, bhh0, hfin, y0f);
    gemm_bias<<<dim3(G3 / TNg, MROWS / TMg), 256, 0, stream>>>(y0f, Wih1, bih1, gibuf, MROWS, G3, HH);
    gru_scan2f<<<dim3(NSEQ / QS), SCTH, 0, stream>>>(gibuf, Whh1, bhh1, hfin, nullptr);
  }

  fc_mean<<<dim3(BB), 256, 0, stream>>>(hfin, fcW, fcb, out);
}